// Round 4
// baseline (780.095 us; speedup 1.0000x reference)
//
#include <hip/hip_runtime.h>
#include <math.h>

// B=1, T=3, C=64, H=W=192, K=7, PS=7, WS=8, WS_R=3, WT=1, STRIDE0=4
// NQH=NQW=48, Q=6912, S=2, QS=13824, R=9.
#define HW     36864          // 192*192
#define ROWF   12288          // 192*64 floats per image row (channels-last)
#define NEGINF (-3.402823e38f)

__device__ __forceinline__ int refl(int i, int n) {
    i = (i < 0) ? -i : i;
    return (i >= n) ? (2 * n - 2 - i) : i;
}

// ---------------------------------------------------------------------------
// Stage 0: permute vid0/vid1 from [t][c][h][w] to [t][h][w][c] (channels-last).
// ---------------------------------------------------------------------------
__global__ void k_permute(const float* __restrict__ vid0,
                          const float* __restrict__ vid1,
                          float* __restrict__ v0p, float* __restrict__ v1p)
{
    const int tid = threadIdx.x;           // 256
    const int bid = blockIdx.x;            // 3456 = 2 vids * 3 t * 576 tiles
    const int vb  = bid / 1728;
    const int r   = bid - vb * 1728;
    const int t   = r / 576;
    const int p0  = (r - t * 576) * 64;    // hw tile base

    const float* in = (vb == 0 ? vid0 : vid1) + (size_t)t * 64 * HW;
    float* out      = (vb == 0 ? v0p  : v1p ) + (size_t)t * HW * 64;

    __shared__ float tile[64][65];
#pragma unroll
    for (int i = 0; i < 16; ++i) {
        int idx = i * 256 + tid;
        int c   = idx >> 6;
        int po  = idx & 63;
        tile[c][po] = in[(size_t)c * HW + p0 + po];
    }
    __syncthreads();
#pragma unroll
    for (int i = 0; i < 16; ++i) {
        int idx = i * 256 + tid;
        int po  = idx >> 6;
        int c   = idx & 63;
        out[(size_t)(p0 + po) * 64 + c] = tile[c][po];
    }
}

// ---------------------------------------------------------------------------
// Stage 1: exact search. UNCHANGED from round 3 (summation order preserved).
// ---------------------------------------------------------------------------
__global__ __launch_bounds__(256)
void k_exact(const float* __restrict__ v0p, const float* __restrict__ v1p,
             float* __restrict__ out_d, float* __restrict__ out_i,
             int* __restrict__ inds_e)
{
    const int tid  = threadIdx.x;
    const int wv   = tid >> 6;
    const int lane = tid & 63;
    const int bid  = blockIdx.x;
    const int swz  = (bid & 7) * 216 + (bid >> 3);   // 1728 blocks, bijective
    const int q    = swz * 4 + wv;                   // < 6912
    const int tq   = q / 2304;
    const int rem  = q - tq * 2304;
    const int hq   = (rem / 48) * 4;
    const int wq   = (rem % 48) * 4;
    const int dh   = lane >> 3;   // delta row group (delta = dh-4)
    const int cp   = lane & 7;    // channel octet

    int w1o[14];
#pragma unroll
    for (int i = 0; i < 14; ++i) w1o[i] = refl(wq + i - 7, 192) * 64;

    float acc[8];
#pragma unroll
    for (int i = 0; i < 8; ++i) acc[i] = 0.f;

    const float* b0 = v0p + (size_t)tq * HW * 64;
    const float* b1 = v1p + (size_t)tq * HW * 64;

#pragma unroll
    for (int j4 = 0; j4 < 2; ++j4) {       // channel quad within octet
        const int co = cp * 8 + j4 * 4;
#pragma unroll
        for (int y = 0; y < 7; ++y) {
            const float* p0 = b0 + refl(hq + y - 3, 192) * ROWF + co;
            const float* p1 = b1 + refl(hq + y + dh - 7, 192) * ROWF + co;
            float4 pr[7];
#pragma unroll
            for (int x0 = 0; x0 < 7; ++x0)
                pr[x0] = *(const float4*)(p0 + refl(wq + x0 - 3, 192) * 64);
#pragma unroll
            for (int x1 = 0; x1 < 14; ++x1) {
                float4 rv = *(const float4*)(p1 + w1o[x1]);
#pragma unroll
                for (int dw = 0; dw < 8; ++dw) {
                    const int x0 = x1 - dw;
                    if (x0 >= 0 && x0 < 7)
                        acc[dw] += pr[x0].x * rv.x + pr[x0].y * rv.y
                                 + pr[x0].z * rv.z + pr[x0].w * rv.w;
                }
            }
        }
    }

#pragma unroll
    for (int m = 1; m < 8; m <<= 1)
#pragma unroll
        for (int i = 0; i < 8; ++i)
            acc[i] += __shfl_xor(acc[i], m, 64);

    float s0 = (cp & 1) ? acc[1] : acc[0];
    float s1 = (cp & 1) ? acc[3] : acc[2];
    float s2 = (cp & 1) ? acc[5] : acc[4];
    float s3 = (cp & 1) ? acc[7] : acc[6];
    float t0 = (cp & 2) ? s1 : s0;
    float t1 = (cp & 2) ? s3 : s2;
    float val = (cp & 4) ? t1 : t0;

    bool taken = false;
    for (int k = 0; k < 7; ++k) {
        float cv = taken ? NEGINF : val;
        int ci = lane;
#pragma unroll
        for (int m = 1; m < 64; m <<= 1) {
            float ov = __shfl_xor(cv, m, 64);
            int   oi = __shfl_xor(ci, m, 64);
            if (ov > cv || (ov == cv && oi < ci)) { cv = ov; ci = oi; }
        }
        if (lane == 0) {
            int dhi = ci >> 3, dwi = ci & 7;
            int hc = refl(hq + dhi - 4, 192);
            int wc = refl(wq + dwi - 4, 192);
            out_d[q * 7 + k] = cv;
            float* o = out_i + (q * 7 + k) * 3;
            o[0] = (float)tq; o[1] = (float)hc; o[2] = (float)wc;
            int* wi = inds_e + (q * 7 + k) * 3;
            wi[0] = tq; wi[1] = hc; wi[2] = wc;
        }
        taken = taken || (lane == ci);
    }
}

// ---------------------------------------------------------------------------
// Stage 2: temporal candidate propagation via rounded flow (round-half-even).
// ---------------------------------------------------------------------------
__global__ void k_temporal(const int* __restrict__ inds_e,
                           const float* __restrict__ fflow,
                           const float* __restrict__ bflow,
                           int* __restrict__ inds_t)
{
    int i = blockIdx.x * blockDim.x + threadIdx.x;  // over Q*K = 48384
    if (i >= 6912 * 7) return;
    int q = i / 7, k = i - 7 * q;
    int t = inds_e[i * 3 + 0], h = inds_e[i * 3 + 1], w = inds_e[i * 3 + 2];
#pragma unroll
    for (int sd = 0; sd < 2; ++sd) {
        const float* fl = (sd == 0) ? fflow : bflow;
        int st = (sd == 0) ? 1 : -1;
        float fx = fl[((t * 2 + 0) * 192 + h) * 192 + w];
        float fy = fl[((t * 2 + 1) * 192 + h) * 192 + w];
        int dx = (int)rintf(fx);
        int dy = (int)rintf(fy);
        int tn = t + st;
        tn = tn < 0 ? 0 : (tn > 2 ? 2 : tn);
        int* o = inds_t + ((q * 2 + sd) * 7 + k) * 3;
        o[0] = tn;
        o[1] = refl(h + dy, 192);
        o[2] = refl(w + dx, 192);
    }
}

// ---------------------------------------------------------------------------
// Stage 3: refine, merged. One wave per qs, lane = channel.
// v0 patch p[7][7] cached in regs ONCE, reused across all 7 candidates.
// Per-k accumulate is bit-identical (same y1->dri->dc->x0 order, same
// shuffle reduce) to round 3; per-k scores go to per-wave LDS, then the
// verified top-7 butterfly runs in-kernel.
// ---------------------------------------------------------------------------
__global__ __launch_bounds__(256)
void k_refine(const float* __restrict__ v0p, const float* __restrict__ v1p,
              const int* __restrict__ inds_t,
              float* __restrict__ out_d, float* __restrict__ out_i)
{
    const int tid  = threadIdx.x;
    const int wv   = tid >> 6;
    const int lane = tid & 63;                        // channel
    const int bid  = blockIdx.x;
    const int swz  = (bid & 7) * 432 + (bid >> 3);    // 3456 blocks, bijective
    const int qs   = swz * 4 + wv;                    // < 13824
    const int q    = qs >> 1;
    const int tq   = q / 2304;
    const int rem  = q - tq * 2304;
    const int hq   = (rem / 48) * 4;
    const int wq   = (rem % 48) * 4;

    __shared__ float sc[4][64];

    // ---- load v0 patch once: p[y][x] for this lane's channel ----
    const float* b0 = v0p + (size_t)tq * HW * 64 + lane;
    int w0o[7];
#pragma unroll
    for (int i = 0; i < 7; ++i) w0o[i] = refl(wq + i - 3, 192) * 64;
    float p[7][7];
#pragma unroll
    for (int y = 0; y < 7; ++y) {
        const float* r0 = b0 + refl(hq + y - 3, 192) * ROWF;
#pragma unroll
        for (int x = 0; x < 7; ++x) p[y][x] = r0[w0o[x]];
    }

    if (lane == 0) sc[wv][63] = NEGINF;

    for (int k = 0; k < 7; ++k) {
        const int* it = inds_t + (qs * 7 + k) * 3;
        const int tc = it[0], hcn = it[1], wcn = it[2];

        int wc9o[9];
#pragma unroll
        for (int i = 0; i < 9; ++i) wc9o[i] = refl(wcn + i - 4, 192) * 64;

        float acc[9];
#pragma unroll
        for (int i = 0; i < 9; ++i) acc[i] = 0.f;

        const float* b1 = v1p + (size_t)tc * HW * 64 + lane;

#pragma unroll
        for (int y1 = 0; y1 < 9; ++y1) {              // v1 region row
            const float* r1 = b1 + refl(hcn + y1 - 4, 192) * ROWF;
            float rv[9];
#pragma unroll
            for (int x1 = 0; x1 < 9; ++x1) rv[x1] = r1[wc9o[x1]];
#pragma unroll
            for (int dri = 0; dri < 3; ++dri) {
                const int y0 = y1 - dri;
                if (y0 >= 0 && y0 <= 6) {
#pragma unroll
                    for (int dc = 0; dc < 3; ++dc)
#pragma unroll
                        for (int x0 = 0; x0 < 7; ++x0)
                            acc[dri * 3 + dc] += p[y0][x0] * rv[x0 + dc];
                }
            }
        }

        // full 64-lane channel reduction (same as round 3)
#pragma unroll
        for (int m = 1; m < 64; m <<= 1)
#pragma unroll
            for (int i = 0; i < 9; ++i)
                acc[i] += __shfl_xor(acc[i], m, 64);

        if (lane == 0) {
#pragma unroll
            for (int r = 0; r < 9; ++r) sc[wv][k * 9 + r] = acc[r];
        }
    }

    __syncthreads();
    float val = sc[wv][lane];   // [63] pre-set to NEGINF

    bool taken = false;
    for (int ksel = 0; ksel < 7; ++ksel) {
        float cv = taken ? NEGINF : val;
        int ci = lane;
#pragma unroll
        for (int m = 1; m < 64; m <<= 1) {
            float ov = __shfl_xor(cv, m, 64);
            int   oi = __shfl_xor(ci, m, 64);
            if (ov > cv || (ov == cv && oi < ci)) { cv = ov; ci = oi; }
        }
        if (lane == 0) {
            int k = ci / 9, r = ci - 9 * k;
            int dri = r / 3, dci = r - 3 * dri;
            const int* itk = inds_t + (qs * 7 + k) * 3;
            int tck = itk[0], hck = itk[1], wck = itk[2];
            int row = 6912 + qs;
            out_d[row * 7 + ksel] = cv;
            float* o = out_i + (row * 7 + ksel) * 3;
            o[0] = (float)tck;
            o[1] = (float)refl(hck + dri - 1, 192);
            o[2] = (float)refl(wck + dci - 1, 192);
        }
        taken = taken || (lane == ci);
    }
}

// ---------------------------------------------------------------------------
extern "C" void kernel_launch(void* const* d_in, const int* in_sizes, int n_in,
                              void* d_out, int out_size, void* d_ws, size_t ws_size,
                              hipStream_t stream)
{
    const float* vid0  = (const float*)d_in[0];
    const float* vid1  = (const float*)d_in[1];
    const float* fflow = (const float*)d_in[2];
    const float* bflow = (const float*)d_in[3];

    float* out   = (float*)d_out;
    float* out_d = out;              // 20736*7 dists
    float* out_i = out + 145152;     // 20736*7*3 inds (as float)

    float* ws     = (float*)d_ws;
    float* v0p    = ws;                        // 3*36864*64 floats
    float* v1p    = ws + 7077888;              // 3*36864*64 floats
    int*   inds_e = (int*)(ws + 14155776);     // 6912*7*3 ints
    int*   inds_t = inds_e + 145152;           // 13824*7*3 ints

    k_permute<<<3456, 256, 0, stream>>>(vid0, vid1, v0p, v1p);
    k_exact<<<1728, 256, 0, stream>>>(v0p, v1p, out_d, out_i, inds_e);
    k_temporal<<<(6912 * 7 + 255) / 256, 256, 0, stream>>>(inds_e, fflow, bflow, inds_t);
    k_refine<<<3456, 256, 0, stream>>>(v0p, v1p, inds_t, out_d, out_i);
}

// Round 6
// 680.170 us; speedup vs baseline: 1.1469x; 1.1469x over previous
//
#include <hip/hip_runtime.h>
#include <math.h>

// B=1, T=3, C=64, H=W=192, K=7, PS=7, WS=8, WS_R=3, WT=1, STRIDE0=4
// NQH=NQW=48, Q=6912, S=2, QS=13824, R=9.
#define HW     36864          // 192*192
#define ROWF   12288          // 192*64 floats per image row (channels-last)
#define NEGINF (-3.402823e38f)

__device__ __forceinline__ int refl(int i, int n) {
    i = (i < 0) ? -i : i;
    return (i >= n) ? (2 * n - 2 - i) : i;
}

// ---------------------------------------------------------------------------
// Stage 0: permute vid0/vid1 from [t][c][h][w] to [t][h][w][c] (channels-last).
// ---------------------------------------------------------------------------
__global__ void k_permute(const float* __restrict__ vid0,
                          const float* __restrict__ vid1,
                          float* __restrict__ v0p, float* __restrict__ v1p)
{
    const int tid = threadIdx.x;           // 256
    const int bid = blockIdx.x;            // 3456 = 2 vids * 3 t * 576 tiles
    const int vb  = bid / 1728;
    const int r   = bid - vb * 1728;
    const int t   = r / 576;
    const int p0  = (r - t * 576) * 64;    // hw tile base

    const float* in = (vb == 0 ? vid0 : vid1) + (size_t)t * 64 * HW;
    float* out      = (vb == 0 ? v0p  : v1p ) + (size_t)t * HW * 64;

    __shared__ float tile[64][65];
#pragma unroll
    for (int i = 0; i < 16; ++i) {
        int idx = i * 256 + tid;
        int c   = idx >> 6;
        int po  = idx & 63;
        tile[c][po] = in[(size_t)c * HW + p0 + po];
    }
    __syncthreads();
#pragma unroll
    for (int i = 0; i < 16; ++i) {
        int idx = i * 256 + tid;
        int po  = idx >> 6;
        int c   = idx & 63;
        out[(size_t)(p0 + po) * 64 + c] = tile[c][po];
    }
}

// ---------------------------------------------------------------------------
// Stage 1: exact search. Same arithmetic order as rounds 3/4; the 14 rv row
// loads are hoisted ahead of the FMA block (independent loads -> deep MLP;
// per-acc accumulation order still x1-ascending -> bit-identical results).
// ---------------------------------------------------------------------------
__global__ __launch_bounds__(256)
void k_exact(const float* __restrict__ v0p, const float* __restrict__ v1p,
             float* __restrict__ out_d, float* __restrict__ out_i,
             int* __restrict__ inds_e)
{
    const int tid  = threadIdx.x;
    const int wv   = tid >> 6;
    const int lane = tid & 63;
    const int bid  = blockIdx.x;
    const int swz  = (bid & 7) * 216 + (bid >> 3);   // 1728 blocks, bijective
    const int q    = swz * 4 + wv;                   // < 6912
    const int tq   = q / 2304;
    const int rem  = q - tq * 2304;
    const int hq   = (rem / 48) * 4;
    const int wq   = (rem % 48) * 4;
    const int dh   = lane >> 3;   // delta row group (delta = dh-4)
    const int cp   = lane & 7;    // channel octet

    int w1o[14];
#pragma unroll
    for (int i = 0; i < 14; ++i) w1o[i] = refl(wq + i - 7, 192) * 64;

    float acc[8];
#pragma unroll
    for (int i = 0; i < 8; ++i) acc[i] = 0.f;

    const float* b0 = v0p + (size_t)tq * HW * 64;
    const float* b1 = v1p + (size_t)tq * HW * 64;

#pragma unroll
    for (int j4 = 0; j4 < 2; ++j4) {       // channel quad within octet
        const int co = cp * 8 + j4 * 4;
#pragma unroll
        for (int y = 0; y < 7; ++y) {
            const float* p0 = b0 + refl(hq + y - 3, 192) * ROWF + co;
            const float* p1 = b1 + refl(hq + y + dh - 7, 192) * ROWF + co;
            float4 pr[7];
#pragma unroll
            for (int x0 = 0; x0 < 7; ++x0)
                pr[x0] = *(const float4*)(p0 + refl(wq + x0 - 3, 192) * 64);
            float4 rv[14];
#pragma unroll
            for (int x1 = 0; x1 < 14; ++x1)
                rv[x1] = *(const float4*)(p1 + w1o[x1]);
#pragma unroll
            for (int x1 = 0; x1 < 14; ++x1) {
#pragma unroll
                for (int dw = 0; dw < 8; ++dw) {
                    const int x0 = x1 - dw;
                    if (x0 >= 0 && x0 < 7)
                        acc[dw] += pr[x0].x * rv[x1].x + pr[x0].y * rv[x1].y
                                 + pr[x0].z * rv[x1].z + pr[x0].w * rv[x1].w;
                }
            }
        }
    }

#pragma unroll
    for (int m = 1; m < 8; m <<= 1)
#pragma unroll
        for (int i = 0; i < 8; ++i)
            acc[i] += __shfl_xor(acc[i], m, 64);

    float s0 = (cp & 1) ? acc[1] : acc[0];
    float s1 = (cp & 1) ? acc[3] : acc[2];
    float s2 = (cp & 1) ? acc[5] : acc[4];
    float s3 = (cp & 1) ? acc[7] : acc[6];
    float t0 = (cp & 2) ? s1 : s0;
    float t1 = (cp & 2) ? s3 : s2;
    float val = (cp & 4) ? t1 : t0;

    bool taken = false;
    for (int k = 0; k < 7; ++k) {
        float cv = taken ? NEGINF : val;
        int ci = lane;
#pragma unroll
        for (int m = 1; m < 64; m <<= 1) {
            float ov = __shfl_xor(cv, m, 64);
            int   oi = __shfl_xor(ci, m, 64);
            if (ov > cv || (ov == cv && oi < ci)) { cv = ov; ci = oi; }
        }
        if (lane == 0) {
            int dhi = ci >> 3, dwi = ci & 7;
            int hc = refl(hq + dhi - 4, 192);
            int wc = refl(wq + dwi - 4, 192);
            out_d[q * 7 + k] = cv;
            float* o = out_i + (q * 7 + k) * 3;
            o[0] = (float)tq; o[1] = (float)hc; o[2] = (float)wc;
            int* wi = inds_e + (q * 7 + k) * 3;
            wi[0] = tq; wi[1] = hc; wi[2] = wc;
        }
        taken = taken || (lane == ci);
    }
}

// ---------------------------------------------------------------------------
// Stage 2: temporal candidate propagation via rounded flow (round-half-even).
// ---------------------------------------------------------------------------
__global__ void k_temporal(const int* __restrict__ inds_e,
                           const float* __restrict__ fflow,
                           const float* __restrict__ bflow,
                           int* __restrict__ inds_t)
{
    int i = blockIdx.x * blockDim.x + threadIdx.x;  // over Q*K = 48384
    if (i >= 6912 * 7) return;
    int q = i / 7, k = i - 7 * q;
    int t = inds_e[i * 3 + 0], h = inds_e[i * 3 + 1], w = inds_e[i * 3 + 2];
#pragma unroll
    for (int sd = 0; sd < 2; ++sd) {
        const float* fl = (sd == 0) ? fflow : bflow;
        int st = (sd == 0) ? 1 : -1;
        float fx = fl[((t * 2 + 0) * 192 + h) * 192 + w];
        float fy = fl[((t * 2 + 1) * 192 + h) * 192 + w];
        int dx = (int)rintf(fx);
        int dy = (int)rintf(fy);
        int tn = t + st;
        tn = tn < 0 ? 0 : (tn > 2 ? 2 : tn);
        int* o = inds_t + ((q * 2 + sd) * 7 + k) * 3;
        o[0] = tn;
        o[1] = refl(h + dy, 192);
        o[2] = refl(w + dx, 192);
    }
}

// ---------------------------------------------------------------------------
// Stage 3a: refine accumulate. One wave per (qs,k) [max TLP], lane = channel.
// v0 patch p[7][7] register-cached per wave (49 loads instead of 147);
// accumulation order bit-identical to rounds 3/4.
// ---------------------------------------------------------------------------
__global__ __launch_bounds__(256)
void k_refine_acc(const float* __restrict__ v0p, const float* __restrict__ v1p,
                  const int* __restrict__ inds_t, float* __restrict__ scores)
{
    const int tid  = threadIdx.x;
    const int wv   = tid >> 6;
    const int lane = tid & 63;                        // channel
    const int bid  = blockIdx.x;
    const int swz  = (bid & 7) * 3024 + (bid >> 3);   // 24192 blocks, bijective
    const int wi   = swz * 4 + wv;                    // < 96768
    const int qs   = wi / 7;
    const int k    = wi - qs * 7;
    const int q    = qs >> 1;
    const int tq   = q / 2304;
    const int rem  = q - tq * 2304;
    const int hq   = (rem / 48) * 4;
    const int wq   = (rem % 48) * 4;

    const int* it = inds_t + (qs * 7 + k) * 3;
    const int tc = it[0], hcn = it[1], wcn = it[2];

    int wc9o[9], w0o[7];
#pragma unroll
    for (int i = 0; i < 9; ++i) wc9o[i] = refl(wcn + i - 4, 192) * 64;
#pragma unroll
    for (int i = 0; i < 7; ++i) w0o[i] = refl(wq + i - 3, 192) * 64;

    // register-cache the v0 patch for this lane's channel (same addresses
    // as rounds 3/4's pr loads -> identical values)
    const float* b0 = v0p + (size_t)tq * HW * 64 + lane;
    float p[7][7];
#pragma unroll
    for (int y = 0; y < 7; ++y) {
        const float* r0 = b0 + refl(hq + y - 3, 192) * ROWF;
#pragma unroll
        for (int x = 0; x < 7; ++x) p[y][x] = r0[w0o[x]];
    }

    float acc[9];
#pragma unroll
    for (int i = 0; i < 9; ++i) acc[i] = 0.f;

    const float* b1 = v1p + (size_t)tc * HW * 64 + lane;

#pragma unroll
    for (int y1 = 0; y1 < 9; ++y1) {                  // v1 region row
        const float* r1 = b1 + refl(hcn + y1 - 4, 192) * ROWF;
        float rv[9];
#pragma unroll
        for (int x1 = 0; x1 < 9; ++x1) rv[x1] = r1[wc9o[x1]];
#pragma unroll
        for (int dri = 0; dri < 3; ++dri) {
            const int y0 = y1 - dri;
            if (y0 >= 0 && y0 <= 6) {
#pragma unroll
                for (int dc = 0; dc < 3; ++dc)
#pragma unroll
                    for (int x0 = 0; x0 < 7; ++x0)
                        acc[dri * 3 + dc] += p[y0][x0] * rv[x0 + dc];
            }
        }
    }

    // full 64-lane channel reduction (identical to rounds 3/4)
#pragma unroll
    for (int m = 1; m < 64; m <<= 1)
#pragma unroll
        for (int i = 0; i < 9; ++i)
            acc[i] += __shfl_xor(acc[i], m, 64);

    if (lane == 0) {
        float* o = scores + (size_t)qs * 64 + k * 9;
#pragma unroll
        for (int r = 0; r < 9; ++r) o[r] = acc[r];
    }
}

// ---------------------------------------------------------------------------
// Stage 3b: refine top-7. One wave per qs. (verified round-3 code)
// ---------------------------------------------------------------------------
__global__ __launch_bounds__(256)
void k_refine_top(const float* __restrict__ scores,
                  const int* __restrict__ inds_t,
                  float* __restrict__ out_d, float* __restrict__ out_i)
{
    const int tid  = threadIdx.x;
    const int wv   = tid >> 6;
    const int lane = tid & 63;
    const int qs   = blockIdx.x * 4 + wv;            // < 13824

    float val = (lane < 63) ? scores[(size_t)qs * 64 + lane] : NEGINF;

    bool taken = false;
    for (int ksel = 0; ksel < 7; ++ksel) {
        float cv = taken ? NEGINF : val;
        int ci = lane;
#pragma unroll
        for (int m = 1; m < 64; m <<= 1) {
            float ov = __shfl_xor(cv, m, 64);
            int   oi = __shfl_xor(ci, m, 64);
            if (ov > cv || (ov == cv && oi < ci)) { cv = ov; ci = oi; }
        }
        if (lane == 0) {
            int k = ci / 9, r = ci - 9 * k;
            int dri = r / 3, dci = r - 3 * dri;
            const int* itk = inds_t + (qs * 7 + k) * 3;
            int tck = itk[0], hck = itk[1], wck = itk[2];
            int row = 6912 + qs;
            out_d[row * 7 + ksel] = cv;
            float* o = out_i + (row * 7 + ksel) * 3;
            o[0] = (float)tck;
            o[1] = (float)refl(hck + dri - 1, 192);
            o[2] = (float)refl(wck + dci - 1, 192);
        }
        taken = taken || (lane == ci);
    }
}

// ---------------------------------------------------------------------------
extern "C" void kernel_launch(void* const* d_in, const int* in_sizes, int n_in,
                              void* d_out, int out_size, void* d_ws, size_t ws_size,
                              hipStream_t stream)
{
    const float* vid0  = (const float*)d_in[0];
    const float* vid1  = (const float*)d_in[1];
    const float* fflow = (const float*)d_in[2];
    const float* bflow = (const float*)d_in[3];

    float* out   = (float*)d_out;
    float* out_d = out;              // 20736*7 dists
    float* out_i = out + 145152;     // 20736*7*3 inds (as float)

    float* ws     = (float*)d_ws;
    float* v0p    = ws;                        // 3*36864*64 floats
    float* v1p    = ws + 7077888;              // 3*36864*64 floats
    float* scores = ws + 14155776;             // 13824*64 floats
    int*   inds_e = (int*)(ws + 15040512);     // 6912*7*3 ints
    int*   inds_t = inds_e + 145152;           // 13824*7*3 ints

    k_permute<<<3456, 256, 0, stream>>>(vid0, vid1, v0p, v1p);
    k_exact<<<1728, 256, 0, stream>>>(v0p, v1p, out_d, out_i, inds_e);
    k_temporal<<<(6912 * 7 + 255) / 256, 256, 0, stream>>>(inds_e, fflow, bflow, inds_t);
    k_refine_acc<<<24192, 256, 0, stream>>>(v0p, v1p, inds_t, scores);
    k_refine_top<<<3456, 256, 0, stream>>>(scores, inds_t, out_d, out_i);
}

// Round 8
// 413.660 us; speedup vs baseline: 1.8858x; 1.6443x over previous
//
#include <hip/hip_runtime.h>
#include <math.h>

// B=1, T=3, C=64, H=W=192, K=7, PS=7, WS=8, WS_R=3, WT=1, STRIDE0=4
// NQH=NQW=48, Q=6912, S=2, QS=13824, R=9.
#define HW     36864          // 192*192
#define ROWF   12288          // 192*64 floats per image row (channels-last)
#define NEGINF (-3.402823e38f)
#define RFL(x) __builtin_amdgcn_readfirstlane(x)

__device__ __forceinline__ int refl(int i, int n) {
    i = (i < 0) ? -i : i;
    return (i >= n) ? (2 * n - 2 - i) : i;
}

// ---------------------------------------------------------------------------
// Stage 0: permute vid0/vid1 from [t][c][h][w] to [t][h][w][c] (channels-last).
// ---------------------------------------------------------------------------
__global__ void k_permute(const float* __restrict__ vid0,
                          const float* __restrict__ vid1,
                          float* __restrict__ v0p, float* __restrict__ v1p)
{
    const int tid = threadIdx.x;           // 256
    const int bid = blockIdx.x;            // 3456 = 2 vids * 3 t * 576 tiles
    const int vb  = bid / 1728;
    const int r   = bid - vb * 1728;
    const int t   = r / 576;
    const int p0  = (r - t * 576) * 64;    // hw tile base

    const float* in = (vb == 0 ? vid0 : vid1) + (size_t)t * 64 * HW;
    float* out      = (vb == 0 ? v0p  : v1p ) + (size_t)t * HW * 64;

    __shared__ float tile[64][65];
#pragma unroll
    for (int i = 0; i < 16; ++i) {
        int idx = i * 256 + tid;
        int c   = idx >> 6;
        int po  = idx & 63;
        tile[c][po] = in[(size_t)c * HW + p0 + po];
    }
    __syncthreads();
#pragma unroll
    for (int i = 0; i < 16; ++i) {
        int idx = i * 256 + tid;
        int po  = idx >> 6;
        int c   = idx & 63;
        out[(size_t)(p0 + po) * 64 + c] = tile[c][po];
    }
}

// ---------------------------------------------------------------------------
// Stage 1: exact search. Arithmetic bit-identical to rounds 3/4/6 (x1
// ascending per acc[dw]); wave-uniform indices forced to SGPRs via
// readfirstlane; rv loaded in two 7-element chunks (order preserved) to cut
// register pressure.
// ---------------------------------------------------------------------------
__global__ __launch_bounds__(256)
void k_exact(const float* __restrict__ v0p, const float* __restrict__ v1p,
             float* __restrict__ out_d, float* __restrict__ out_i,
             int* __restrict__ inds_e)
{
    const int tid  = threadIdx.x;
    const int lane = tid & 63;
    const int wv   = RFL(tid >> 6);                  // scalar
    const int bid  = blockIdx.x;
    const int swz  = (bid & 7) * 216 + (bid >> 3);   // 1728 blocks, bijective
    const int q    = swz * 4 + wv;                   // scalar, < 6912
    const int tq   = q / 2304;
    const int rem  = q - tq * 2304;
    const int hq   = (rem / 48) * 4;
    const int wq   = (rem % 48) * 4;
    const int dh   = lane >> 3;   // per-lane: delta row group (delta = dh-4)
    const int cp   = lane & 7;    // per-lane: channel octet

    int w1o[14];                  // scalar table
#pragma unroll
    for (int i = 0; i < 14; ++i) w1o[i] = refl(wq + i - 7, 192) * 64;
    int w0o[7];                   // scalar table
#pragma unroll
    for (int i = 0; i < 7; ++i) w0o[i] = refl(wq + i - 3, 192) * 64;

    float acc[8];
#pragma unroll
    for (int i = 0; i < 8; ++i) acc[i] = 0.f;

    const float* b0 = v0p + (size_t)tq * HW * 64;    // scalar bases
    const float* b1 = v1p + (size_t)tq * HW * 64;

#pragma unroll
    for (int j4 = 0; j4 < 2; ++j4) {       // channel quad within octet
        const int co = cp * 8 + j4 * 4;    // per-lane element offset
#pragma unroll
        for (int y = 0; y < 7; ++y) {
            const int h0o  = refl(hq + y - 3, 192) * ROWF;       // scalar
            const int h1l  = refl(hq + y + dh - 7, 192) * ROWF;  // per-lane
            float4 pr[7];
#pragma unroll
            for (int x0 = 0; x0 < 7; ++x0)
                pr[x0] = *(const float4*)(b0 + h0o + w0o[x0] + co);
            // chunk A: x1 = 0..6 (same FMA sequence as full-width version)
            {
                float4 rv[7];
#pragma unroll
                for (int x1 = 0; x1 < 7; ++x1)
                    rv[x1] = *(const float4*)(b1 + h1l + w1o[x1] + co);
#pragma unroll
                for (int x1 = 0; x1 < 7; ++x1) {
#pragma unroll
                    for (int dw = 0; dw < 8; ++dw) {
                        const int x0 = x1 - dw;
                        if (x0 >= 0 && x0 < 7)
                            acc[dw] += pr[x0].x * rv[x1].x + pr[x0].y * rv[x1].y
                                     + pr[x0].z * rv[x1].z + pr[x0].w * rv[x1].w;
                    }
                }
            }
            // chunk B: x1 = 7..13
            {
                float4 rv[7];
#pragma unroll
                for (int x1 = 7; x1 < 14; ++x1)
                    rv[x1 - 7] = *(const float4*)(b1 + h1l + w1o[x1] + co);
#pragma unroll
                for (int x1 = 7; x1 < 14; ++x1) {
#pragma unroll
                    for (int dw = 0; dw < 8; ++dw) {
                        const int x0 = x1 - dw;
                        if (x0 >= 0 && x0 < 7)
                            acc[dw] += pr[x0].x * rv[x1 - 7].x + pr[x0].y * rv[x1 - 7].y
                                     + pr[x0].z * rv[x1 - 7].z + pr[x0].w * rv[x1 - 7].w;
                    }
                }
            }
        }
    }

#pragma unroll
    for (int m = 1; m < 8; m <<= 1)
#pragma unroll
        for (int i = 0; i < 8; ++i)
            acc[i] += __shfl_xor(acc[i], m, 64);

    float s0 = (cp & 1) ? acc[1] : acc[0];
    float s1 = (cp & 1) ? acc[3] : acc[2];
    float s2 = (cp & 1) ? acc[5] : acc[4];
    float s3 = (cp & 1) ? acc[7] : acc[6];
    float t0 = (cp & 2) ? s1 : s0;
    float t1 = (cp & 2) ? s3 : s2;
    float val = (cp & 4) ? t1 : t0;

    bool taken = false;
    for (int k = 0; k < 7; ++k) {
        float cv = taken ? NEGINF : val;
        int ci = lane;
#pragma unroll
        for (int m = 1; m < 64; m <<= 1) {
            float ov = __shfl_xor(cv, m, 64);
            int   oi = __shfl_xor(ci, m, 64);
            if (ov > cv || (ov == cv && oi < ci)) { cv = ov; ci = oi; }
        }
        if (lane == 0) {
            int dhi = ci >> 3, dwi = ci & 7;
            int hc = refl(hq + dhi - 4, 192);
            int wc = refl(wq + dwi - 4, 192);
            out_d[q * 7 + k] = cv;
            float* o = out_i + (q * 7 + k) * 3;
            o[0] = (float)tq; o[1] = (float)hc; o[2] = (float)wc;
            int* wi = inds_e + (q * 7 + k) * 3;
            wi[0] = tq; wi[1] = hc; wi[2] = wc;
        }
        taken = taken || (lane == ci);
    }
}

// ---------------------------------------------------------------------------
// Stage 2: temporal candidate propagation via rounded flow (round-half-even).
// ---------------------------------------------------------------------------
__global__ void k_temporal(const int* __restrict__ inds_e,
                           const float* __restrict__ fflow,
                           const float* __restrict__ bflow,
                           int* __restrict__ inds_t)
{
    int i = blockIdx.x * blockDim.x + threadIdx.x;  // over Q*K = 48384
    if (i >= 6912 * 7) return;
    int q = i / 7, k = i - 7 * q;
    int t = inds_e[i * 3 + 0], h = inds_e[i * 3 + 1], w = inds_e[i * 3 + 2];
#pragma unroll
    for (int sd = 0; sd < 2; ++sd) {
        const float* fl = (sd == 0) ? fflow : bflow;
        int st = (sd == 0) ? 1 : -1;
        float fx = fl[((t * 2 + 0) * 192 + h) * 192 + w];
        float fy = fl[((t * 2 + 1) * 192 + h) * 192 + w];
        int dx = (int)rintf(fx);
        int dy = (int)rintf(fy);
        int tn = t + st;
        tn = tn < 0 ? 0 : (tn > 2 ? 2 : tn);
        int* o = inds_t + ((q * 2 + sd) * 7 + k) * 3;
        o[0] = tn;
        o[1] = refl(h + dy, 192);
        o[2] = refl(w + dx, 192);
    }
}

// ---------------------------------------------------------------------------
// Stage 3a: refine accumulate. One wave per (qs,k), lane = channel.
// Round-3 loop structure (transient pr per (y1,dri)); all wave-uniform
// state scalarized -> small VGPR live set -> high occupancy. Arithmetic
// order bit-identical to rounds 3/4/6.
// ---------------------------------------------------------------------------
__global__ __launch_bounds__(256)
void k_refine_acc(const float* __restrict__ v0p, const float* __restrict__ v1p,
                  const int* __restrict__ inds_t, float* __restrict__ scores)
{
    const int tid  = threadIdx.x;
    const int lane = tid & 63;                        // channel (per-lane)
    const int wv   = RFL(tid >> 6);                   // scalar
    const int bid  = blockIdx.x;
    const int swz  = (bid & 7) * 3024 + (bid >> 3);   // 24192 blocks, bijective
    const int wi   = swz * 4 + wv;                    // scalar, < 96768
    const int qs   = wi / 7;
    const int k    = wi - qs * 7;
    const int q    = qs >> 1;
    const int tq   = q / 2304;
    const int rem  = q - tq * 2304;
    const int hq   = (rem / 48) * 4;
    const int wq   = (rem % 48) * 4;

    const int* it = inds_t + (qs * 7 + k) * 3;
    const int tc  = RFL(it[0]);                       // scalar coords
    const int hcn = RFL(it[1]);
    const int wcn = RFL(it[2]);

    int wc9o[9], w0o[7];                              // scalar tables
#pragma unroll
    for (int i = 0; i < 9; ++i) wc9o[i] = refl(wcn + i - 4, 192) * 64;
#pragma unroll
    for (int i = 0; i < 7; ++i) w0o[i] = refl(wq + i - 3, 192) * 64;

    float acc[9];
#pragma unroll
    for (int i = 0; i < 9; ++i) acc[i] = 0.f;

    const float* b0 = v0p + (size_t)tq * HW * 64;     // scalar bases
    const float* b1 = v1p + (size_t)tc * HW * 64;

#pragma unroll
    for (int y1 = 0; y1 < 9; ++y1) {                  // v1 region row
        const int r1o = refl(hcn + y1 - 4, 192) * ROWF;   // scalar
        float rv[9];
#pragma unroll
        for (int x1 = 0; x1 < 9; ++x1) rv[x1] = b1[r1o + wc9o[x1] + lane];
#pragma unroll
        for (int dri = 0; dri < 3; ++dri) {
            const int y0 = y1 - dri;
            if (y0 >= 0 && y0 <= 6) {
                const int r0o = refl(hq + y0 - 3, 192) * ROWF;  // scalar
                float pr[7];
#pragma unroll
                for (int x0 = 0; x0 < 7; ++x0) pr[x0] = b0[r0o + w0o[x0] + lane];
#pragma unroll
                for (int dc = 0; dc < 3; ++dc)
#pragma unroll
                    for (int x0 = 0; x0 < 7; ++x0)
                        acc[dri * 3 + dc] += pr[x0] * rv[x0 + dc];
            }
        }
    }

    // full 64-lane channel reduction (identical to rounds 3/4/6)
#pragma unroll
    for (int m = 1; m < 64; m <<= 1)
#pragma unroll
        for (int i = 0; i < 9; ++i)
            acc[i] += __shfl_xor(acc[i], m, 64);

    if (lane == 0) {
        float* o = scores + (size_t)qs * 64 + k * 9;
#pragma unroll
        for (int r = 0; r < 9; ++r) o[r] = acc[r];
    }
}

// ---------------------------------------------------------------------------
// Stage 3b: refine top-7. One wave per qs. (verified round-3 code)
// ---------------------------------------------------------------------------
__global__ __launch_bounds__(256)
void k_refine_top(const float* __restrict__ scores,
                  const int* __restrict__ inds_t,
                  float* __restrict__ out_d, float* __restrict__ out_i)
{
    const int tid  = threadIdx.x;
    const int wv   = tid >> 6;
    const int lane = tid & 63;
    const int qs   = blockIdx.x * 4 + wv;            // < 13824

    float val = (lane < 63) ? scores[(size_t)qs * 64 + lane] : NEGINF;

    bool taken = false;
    for (int ksel = 0; ksel < 7; ++ksel) {
        float cv = taken ? NEGINF : val;
        int ci = lane;
#pragma unroll
        for (int m = 1; m < 64; m <<= 1) {
            float ov = __shfl_xor(cv, m, 64);
            int   oi = __shfl_xor(ci, m, 64);
            if (ov > cv || (ov == cv && oi < ci)) { cv = ov; ci = oi; }
        }
        if (lane == 0) {
            int k = ci / 9, r = ci - 9 * k;
            int dri = r / 3, dci = r - 3 * dri;
            const int* itk = inds_t + (qs * 7 + k) * 3;
            int tck = itk[0], hck = itk[1], wck = itk[2];
            int row = 6912 + qs;
            out_d[row * 7 + ksel] = cv;
            float* o = out_i + (row * 7 + ksel) * 3;
            o[0] = (float)tck;
            o[1] = (float)refl(hck + dri - 1, 192);
            o[2] = (float)refl(wck + dci - 1, 192);
        }
        taken = taken || (lane == ci);
    }
}

// ---------------------------------------------------------------------------
extern "C" void kernel_launch(void* const* d_in, const int* in_sizes, int n_in,
                              void* d_out, int out_size, void* d_ws, size_t ws_size,
                              hipStream_t stream)
{
    const float* vid0  = (const float*)d_in[0];
    const float* vid1  = (const float*)d_in[1];
    const float* fflow = (const float*)d_in[2];
    const float* bflow = (const float*)d_in[3];

    float* out   = (float*)d_out;
    float* out_d = out;              // 20736*7 dists
    float* out_i = out + 145152;     // 20736*7*3 inds (as float)

    float* ws     = (float*)d_ws;
    float* v0p    = ws;                        // 3*36864*64 floats
    float* v1p    = ws + 7077888;              // 3*36864*64 floats
    float* scores = ws + 14155776;             // 13824*64 floats
    int*   inds_e = (int*)(ws + 15040512);     // 6912*7*3 ints
    int*   inds_t = inds_e + 145152;           // 13824*7*3 ints

    k_permute<<<3456, 256, 0, stream>>>(vid0, vid1, v0p, v1p);
    k_exact<<<1728, 256, 0, stream>>>(v0p, v1p, out_d, out_i, inds_e);
    k_temporal<<<(6912 * 7 + 255) / 256, 256, 0, stream>>>(inds_e, fflow, bflow, inds_t);
    k_refine_acc<<<24192, 256, 0, stream>>>(v0p, v1p, inds_t, scores);
    k_refine_top<<<3456, 256, 0, stream>>>(scores, inds_t, out_d, out_i);
}

// Round 9
// 388.182 us; speedup vs baseline: 2.0096x; 1.0656x over previous
//
#include <hip/hip_runtime.h>
#include <math.h>

// B=1, T=3, C=64, H=W=192, K=7, PS=7, WS=8, WS_R=3, WT=1, STRIDE0=4
// NQH=NQW=48, Q=6912, S=2, QS=13824, R=9.
#define HW     36864          // 192*192
#define ROWF   12288          // 192*64 floats per image row (channels-last)
#define NEGINF (-3.402823e38f)
#define RFL(x) __builtin_amdgcn_readfirstlane(x)

__device__ __forceinline__ int refl(int i, int n) {
    i = (i < 0) ? -i : i;
    return (i >= n) ? (2 * n - 2 - i) : i;
}

// ---------------------------------------------------------------------------
// Stage 0: permute vid0/vid1 from [t][c][h][w] to [t][h][w][c] (channels-last).
// ---------------------------------------------------------------------------
__global__ void k_permute(const float* __restrict__ vid0,
                          const float* __restrict__ vid1,
                          float* __restrict__ v0p, float* __restrict__ v1p)
{
    const int tid = threadIdx.x;           // 256
    const int bid = blockIdx.x;            // 3456 = 2 vids * 3 t * 576 tiles
    const int vb  = bid / 1728;
    const int r   = bid - vb * 1728;
    const int t   = r / 576;
    const int p0  = (r - t * 576) * 64;    // hw tile base

    const float* in = (vb == 0 ? vid0 : vid1) + (size_t)t * 64 * HW;
    float* out      = (vb == 0 ? v0p  : v1p ) + (size_t)t * HW * 64;

    __shared__ float tile[64][65];
#pragma unroll
    for (int i = 0; i < 16; ++i) {
        int idx = i * 256 + tid;
        int c   = idx >> 6;
        int po  = idx & 63;
        tile[c][po] = in[(size_t)c * HW + p0 + po];
    }
    __syncthreads();
#pragma unroll
    for (int i = 0; i < 16; ++i) {
        int idx = i * 256 + tid;
        int po  = idx >> 6;
        int c   = idx & 63;
        out[(size_t)(p0 + po) * 64 + c] = tile[c][po];
    }
}

// ---------------------------------------------------------------------------
// Stage 1: exact search. Arithmetic bit-identical to round 8; every load is
// now (scalar base)[per-lane offset] so the compiler emits saddr+voffset
// global loads with no per-load VALU address math.
// ---------------------------------------------------------------------------
__global__ __launch_bounds__(256)
void k_exact(const float* __restrict__ v0p, const float* __restrict__ v1p,
             float* __restrict__ out_d, float* __restrict__ out_i,
             int* __restrict__ inds_e)
{
    const int tid  = threadIdx.x;
    const int lane = tid & 63;
    const int wv   = RFL(tid >> 6);                  // scalar
    const int bid  = blockIdx.x;
    const int swz  = (bid & 7) * 216 + (bid >> 3);   // 1728 blocks, bijective
    const int q    = swz * 4 + wv;                   // scalar, < 6912
    const int tq   = q / 2304;
    const int rem  = q - tq * 2304;
    const int hq   = (rem / 48) * 4;
    const int wq   = (rem % 48) * 4;
    const int dh   = lane >> 3;   // per-lane: delta row group (delta = dh-4)
    const int cp   = lane & 7;    // per-lane: channel octet

    int w1o[14];                  // scalar table
#pragma unroll
    for (int i = 0; i < 14; ++i) w1o[i] = refl(wq + i - 7, 192) * 64;
    int w0o[7];                   // scalar table
#pragma unroll
    for (int i = 0; i < 7; ++i) w0o[i] = refl(wq + i - 3, 192) * 64;

    float acc[8];
#pragma unroll
    for (int i = 0; i < 8; ++i) acc[i] = 0.f;

    const float* b0 = v0p + (size_t)tq * HW * 64;    // scalar bases
    const float* b1 = v1p + (size_t)tq * HW * 64;

#pragma unroll
    for (int j4 = 0; j4 < 2; ++j4) {       // channel quad within octet
        const int co = cp * 8 + j4 * 4;    // per-lane element offset
#pragma unroll
        for (int y = 0; y < 7; ++y) {
            const int h0o = refl(hq + y - 3, 192) * ROWF;        // scalar
            const int vo  = refl(hq + y + dh - 7, 192) * ROWF + co; // per-lane
            float4 pr[7];
#pragma unroll
            for (int x0 = 0; x0 < 7; ++x0)
                pr[x0] = *(const float4*)((b0 + h0o + w0o[x0]) + co);
            // chunk A: x1 = 0..6 (same FMA sequence as round 8)
            {
                float4 rv[7];
#pragma unroll
                for (int x1 = 0; x1 < 7; ++x1)
                    rv[x1] = *(const float4*)((b1 + w1o[x1]) + vo);
#pragma unroll
                for (int x1 = 0; x1 < 7; ++x1) {
#pragma unroll
                    for (int dw = 0; dw < 8; ++dw) {
                        const int x0 = x1 - dw;
                        if (x0 >= 0 && x0 < 7)
                            acc[dw] += pr[x0].x * rv[x1].x + pr[x0].y * rv[x1].y
                                     + pr[x0].z * rv[x1].z + pr[x0].w * rv[x1].w;
                    }
                }
            }
            // chunk B: x1 = 7..13
            {
                float4 rv[7];
#pragma unroll
                for (int x1 = 7; x1 < 14; ++x1)
                    rv[x1 - 7] = *(const float4*)((b1 + w1o[x1]) + vo);
#pragma unroll
                for (int x1 = 7; x1 < 14; ++x1) {
#pragma unroll
                    for (int dw = 0; dw < 8; ++dw) {
                        const int x0 = x1 - dw;
                        if (x0 >= 0 && x0 < 7)
                            acc[dw] += pr[x0].x * rv[x1 - 7].x + pr[x0].y * rv[x1 - 7].y
                                     + pr[x0].z * rv[x1 - 7].z + pr[x0].w * rv[x1 - 7].w;
                    }
                }
            }
        }
    }

#pragma unroll
    for (int m = 1; m < 8; m <<= 1)
#pragma unroll
        for (int i = 0; i < 8; ++i)
            acc[i] += __shfl_xor(acc[i], m, 64);

    float s0 = (cp & 1) ? acc[1] : acc[0];
    float s1 = (cp & 1) ? acc[3] : acc[2];
    float s2 = (cp & 1) ? acc[5] : acc[4];
    float s3 = (cp & 1) ? acc[7] : acc[6];
    float t0 = (cp & 2) ? s1 : s0;
    float t1 = (cp & 2) ? s3 : s2;
    float val = (cp & 4) ? t1 : t0;

    bool taken = false;
    for (int k = 0; k < 7; ++k) {
        float cv = taken ? NEGINF : val;
        int ci = lane;
#pragma unroll
        for (int m = 1; m < 64; m <<= 1) {
            float ov = __shfl_xor(cv, m, 64);
            int   oi = __shfl_xor(ci, m, 64);
            if (ov > cv || (ov == cv && oi < ci)) { cv = ov; ci = oi; }
        }
        if (lane == 0) {
            int dhi = ci >> 3, dwi = ci & 7;
            int hc = refl(hq + dhi - 4, 192);
            int wc = refl(wq + dwi - 4, 192);
            out_d[q * 7 + k] = cv;
            float* o = out_i + (q * 7 + k) * 3;
            o[0] = (float)tq; o[1] = (float)hc; o[2] = (float)wc;
            int* wi = inds_e + (q * 7 + k) * 3;
            wi[0] = tq; wi[1] = hc; wi[2] = wc;
        }
        taken = taken || (lane == ci);
    }
}

// ---------------------------------------------------------------------------
// Stage 2: temporal candidate propagation via rounded flow (round-half-even).
// ---------------------------------------------------------------------------
__global__ void k_temporal(const int* __restrict__ inds_e,
                           const float* __restrict__ fflow,
                           const float* __restrict__ bflow,
                           int* __restrict__ inds_t)
{
    int i = blockIdx.x * blockDim.x + threadIdx.x;  // over Q*K = 48384
    if (i >= 6912 * 7) return;
    int q = i / 7, k = i - 7 * q;
    int t = inds_e[i * 3 + 0], h = inds_e[i * 3 + 1], w = inds_e[i * 3 + 2];
#pragma unroll
    for (int sd = 0; sd < 2; ++sd) {
        const float* fl = (sd == 0) ? fflow : bflow;
        int st = (sd == 0) ? 1 : -1;
        float fx = fl[((t * 2 + 0) * 192 + h) * 192 + w];
        float fy = fl[((t * 2 + 1) * 192 + h) * 192 + w];
        int dx = (int)rintf(fx);
        int dy = (int)rintf(fy);
        int tn = t + st;
        tn = tn < 0 ? 0 : (tn > 2 ? 2 : tn);
        int* o = inds_t + ((q * 2 + sd) * 7 + k) * 3;
        o[0] = tn;
        o[1] = refl(h + dy, 192);
        o[2] = refl(w + dx, 192);
    }
}

// ---------------------------------------------------------------------------
// Stage 3a: refine accumulate. One wave per (qs,k), lane = channel.
// Round-8 structure; loads rewritten as (scalar base)[lane] so address math
// lives on the scalar unit. Arithmetic order bit-identical to rounds 3-8.
// ---------------------------------------------------------------------------
__global__ __launch_bounds__(256)
void k_refine_acc(const float* __restrict__ v0p, const float* __restrict__ v1p,
                  const int* __restrict__ inds_t, float* __restrict__ scores)
{
    const int tid  = threadIdx.x;
    const int lane = tid & 63;                        // channel (per-lane)
    const int wv   = RFL(tid >> 6);                   // scalar
    const int bid  = blockIdx.x;
    const int swz  = (bid & 7) * 3024 + (bid >> 3);   // 24192 blocks, bijective
    const int wi   = swz * 4 + wv;                    // scalar, < 96768
    const int qs   = wi / 7;
    const int k    = wi - qs * 7;
    const int q    = qs >> 1;
    const int tq   = q / 2304;
    const int rem  = q - tq * 2304;
    const int hq   = (rem / 48) * 4;
    const int wq   = (rem % 48) * 4;

    const int* it = inds_t + (qs * 7 + k) * 3;
    const int tc  = RFL(it[0]);                       // scalar coords
    const int hcn = RFL(it[1]);
    const int wcn = RFL(it[2]);

    int wc9o[9], w0o[7];                              // scalar tables
#pragma unroll
    for (int i = 0; i < 9; ++i) wc9o[i] = refl(wcn + i - 4, 192) * 64;
#pragma unroll
    for (int i = 0; i < 7; ++i) w0o[i] = refl(wq + i - 3, 192) * 64;

    float acc[9];
#pragma unroll
    for (int i = 0; i < 9; ++i) acc[i] = 0.f;

    const float* b0 = v0p + (size_t)tq * HW * 64;     // scalar bases
    const float* b1 = v1p + (size_t)tc * HW * 64;

#pragma unroll
    for (int y1 = 0; y1 < 9; ++y1) {                  // v1 region row
        const int r1o = refl(hcn + y1 - 4, 192) * ROWF;   // scalar
        float rv[9];
#pragma unroll
        for (int x1 = 0; x1 < 9; ++x1) rv[x1] = (b1 + r1o + wc9o[x1])[lane];
#pragma unroll
        for (int dri = 0; dri < 3; ++dri) {
            const int y0 = y1 - dri;
            if (y0 >= 0 && y0 <= 6) {
                const int r0o = refl(hq + y0 - 3, 192) * ROWF;  // scalar
                float pr[7];
#pragma unroll
                for (int x0 = 0; x0 < 7; ++x0) pr[x0] = (b0 + r0o + w0o[x0])[lane];
#pragma unroll
                for (int dc = 0; dc < 3; ++dc)
#pragma unroll
                    for (int x0 = 0; x0 < 7; ++x0)
                        acc[dri * 3 + dc] += pr[x0] * rv[x0 + dc];
            }
        }
    }

    // full 64-lane channel reduction (identical to rounds 3-8)
#pragma unroll
    for (int m = 1; m < 64; m <<= 1)
#pragma unroll
        for (int i = 0; i < 9; ++i)
            acc[i] += __shfl_xor(acc[i], m, 64);

    if (lane == 0) {
        float* o = scores + (size_t)qs * 64 + k * 9;
#pragma unroll
        for (int r = 0; r < 9; ++r) o[r] = acc[r];
    }
}

// ---------------------------------------------------------------------------
// Stage 3b: refine top-7. One wave per qs. (verified round-3 code)
// ---------------------------------------------------------------------------
__global__ __launch_bounds__(256)
void k_refine_top(const float* __restrict__ scores,
                  const int* __restrict__ inds_t,
                  float* __restrict__ out_d, float* __restrict__ out_i)
{
    const int tid  = threadIdx.x;
    const int wv   = tid >> 6;
    const int lane = tid & 63;
    const int qs   = blockIdx.x * 4 + wv;            // < 13824

    float val = (lane < 63) ? scores[(size_t)qs * 64 + lane] : NEGINF;

    bool taken = false;
    for (int ksel = 0; ksel < 7; ++ksel) {
        float cv = taken ? NEGINF : val;
        int ci = lane;
#pragma unroll
        for (int m = 1; m < 64; m <<= 1) {
            float ov = __shfl_xor(cv, m, 64);
            int   oi = __shfl_xor(ci, m, 64);
            if (ov > cv || (ov == cv && oi < ci)) { cv = ov; ci = oi; }
        }
        if (lane == 0) {
            int k = ci / 9, r = ci - 9 * k;
            int dri = r / 3, dci = r - 3 * dri;
            const int* itk = inds_t + (qs * 7 + k) * 3;
            int tck = itk[0], hck = itk[1], wck = itk[2];
            int row = 6912 + qs;
            out_d[row * 7 + ksel] = cv;
            float* o = out_i + (row * 7 + ksel) * 3;
            o[0] = (float)tck;
            o[1] = (float)refl(hck + dri - 1, 192);
            o[2] = (float)refl(wck + dci - 1, 192);
        }
        taken = taken || (lane == ci);
    }
}

// ---------------------------------------------------------------------------
extern "C" void kernel_launch(void* const* d_in, const int* in_sizes, int n_in,
                              void* d_out, int out_size, void* d_ws, size_t ws_size,
                              hipStream_t stream)
{
    const float* vid0  = (const float*)d_in[0];
    const float* vid1  = (const float*)d_in[1];
    const float* fflow = (const float*)d_in[2];
    const float* bflow = (const float*)d_in[3];

    float* out   = (float*)d_out;
    float* out_d = out;              // 20736*7 dists
    float* out_i = out + 145152;     // 20736*7*3 inds (as float)

    float* ws     = (float*)d_ws;
    float* v0p    = ws;                        // 3*36864*64 floats
    float* v1p    = ws + 7077888;              // 3*36864*64 floats
    float* scores = ws + 14155776;             // 13824*64 floats
    int*   inds_e = (int*)(ws + 15040512);     // 6912*7*3 ints
    int*   inds_t = inds_e + 145152;           // 13824*7*3 ints

    k_permute<<<3456, 256, 0, stream>>>(vid0, vid1, v0p, v1p);
    k_exact<<<1728, 256, 0, stream>>>(v0p, v1p, out_d, out_i, inds_e);
    k_temporal<<<(6912 * 7 + 255) / 256, 256, 0, stream>>>(inds_e, fflow, bflow, inds_t);
    k_refine_acc<<<24192, 256, 0, stream>>>(v0p, v1p, inds_t, scores);
    k_refine_top<<<3456, 256, 0, stream>>>(scores, inds_t, out_d, out_i);
}